// Round 10
// baseline (193.533 us; speedup 1.0000x reference)
//
#include <hip/hip_runtime.h>

// MultiHeadAttention: B=1, S=4096, D=768, H=12, HD=64, causal, fp32 in/out.
// Round 9: attn k-loop restructured to single-barrier double-buffered
// staging. Block = 64 q-rows (causal pair qt=bx & 127-bx), 4 waves = 4
// independent 16-row q-subtiles (no kv split -> no combine phase). 64-wide
// kv tiles, K/V dbuf in LDS (50 KB total, 3 blocks/CU). Per tile: one
// barrier; prefetch tile kt+1 via global_load_lds into the other buffer;
// compute tile kt -> the vmcnt drain overlaps a full tile of compute.
// Inner QK/softmax/Pl/PV code verbatim from the proven 76-us kernel.
// GEMMs/prep unchanged (R5/R8 config).

typedef short bf16x8 __attribute__((ext_vector_type(8)));
typedef float f32x4 __attribute__((ext_vector_type(4)));
typedef unsigned short u16;

static constexpr int S_LEN = 4096;
static constexpr int DIM   = 768;
static constexpr int NH    = 12;
// softmax scale folded into Q projection: 1/sqrt(64) * log2(e)
static constexpr float QSCALE = 0.125f * 1.44269504088896340736f;

__device__ inline u16 f2bf(float f) {
  union { float f; unsigned int u; } v; v.f = f;
  unsigned int r = v.u + 0x7FFFu + ((v.u >> 16) & 1u);  // RNE
  return (u16)(r >> 16);
}

__device__ inline void gload_lds16(const u16* g, u16* s) {
  __builtin_amdgcn_global_load_lds(
      (const __attribute__((address_space(1))) unsigned int*)g,
      (__attribute__((address_space(3))) unsigned int*)s, 16, 0, 0);
}

// ---------------------------------------------------------------------------
// Prep: z<4 -> transpose W[z] fp32 -> bf16 W^T; z==4 -> convert x -> bf16.
__global__ __launch_bounds__(256)
void prep_kernel(const float* __restrict__ x, const float* __restrict__ w0,
                 const float* __restrict__ w1, const float* __restrict__ w2,
                 const float* __restrict__ w3, u16* __restrict__ xb,
                 u16* __restrict__ t0, u16* __restrict__ t1,
                 u16* __restrict__ t2, u16* __restrict__ t3) {
  if (blockIdx.z == 4) {
    const size_t n = (size_t)S_LEN * DIM;
    const int id = blockIdx.y * 12 + blockIdx.x;
    const size_t stride = (size_t)144 * 256 * 8;
    for (size_t i = ((size_t)id * 256 + threadIdx.x) * 8; i < n; i += stride) {
      const float4 a = *(const float4*)(x + i);
      const float4 b = *(const float4*)(x + i + 4);
      bf16x8 o;
      o[0] = (short)f2bf(a.x); o[1] = (short)f2bf(a.y);
      o[2] = (short)f2bf(a.z); o[3] = (short)f2bf(a.w);
      o[4] = (short)f2bf(b.x); o[5] = (short)f2bf(b.y);
      o[6] = (short)f2bf(b.z); o[7] = (short)f2bf(b.w);
      *(bf16x8*)(xb + i) = o;
    }
    return;
  }
  __shared__ float T[64][65];
  const float* src; u16* dst;
  switch (blockIdx.z) {
    case 0: src = w0; dst = t0; break;
    case 1: src = w1; dst = t1; break;
    case 2: src = w2; dst = t2; break;
    default: src = w3; dst = t3; break;
  }
  const int k0 = blockIdx.y * 64, n0 = blockIdx.x * 64;
  const int r = threadIdx.x >> 2, c0 = (threadIdx.x & 3) * 16;
#pragma unroll
  for (int i = 0; i < 4; ++i) {
    const float4 v = *(const float4*)(src + (size_t)(k0 + r) * DIM + n0 + c0 + i * 4);
    T[r][c0 + i * 4 + 0] = v.x;
    T[r][c0 + i * 4 + 1] = v.y;
    T[r][c0 + i * 4 + 2] = v.z;
    T[r][c0 + i * 4 + 3] = v.w;
  }
  __syncthreads();
  bf16x8 o0, o1;
#pragma unroll
  for (int i = 0; i < 8; ++i) {
    o0[i] = (short)f2bf(T[c0 + i][r]);
    o1[i] = (short)f2bf(T[c0 + 8 + i][r]);
  }
  *(bf16x8*)(dst + (size_t)(n0 + r) * DIM + k0 + c0) = o0;
  *(bf16x8*)(dst + (size_t)(n0 + r) * DIM + k0 + c0 + 8) = o1;
}

// ---------------------------------------------------------------------------
// MFMA GEMM, BK=64, BN=96, global_load_lds staging with XOR chunk swizzle.
// MODE 0: fused QKV (BM=128, grid 24x32 = 768 blocks = 3/CU). wi = n0/768:
//         Q (scaled), K row-major bf16; V -> VT[768][4096].
// MODE 1: out GEMM (BM=64, grid 8x64 = 512 blocks), fp32 + bias.
template <int MODE>
__global__ __launch_bounds__(256)
void mfma_gemm_kernel(const u16* __restrict__ A, const u16* __restrict__ Bq,
                      const u16* __restrict__ Bk, const u16* __restrict__ Bv,
                      const float* __restrict__ bias, u16* __restrict__ Qb,
                      u16* __restrict__ Kb, u16* __restrict__ VT,
                      float* __restrict__ Out) {
  constexpr int MT = (MODE == 0) ? 4 : 2;   // m-frags (16) per wave
  constexpr int BM = MT * 32;
  __shared__ __align__(16) u16 Al[BM * 64];
  __shared__ __align__(16) u16 Bl[96 * 64];

  const int tid  = threadIdx.x;
  const int wv   = tid >> 6;
  const int lane = tid & 63;
  const int quad = lane >> 4;
  const int l16  = lane & 15;
  const int wr = wv >> 1, wc = wv & 1;
  const int m0 = blockIdx.y * BM;
  const int n0 = blockIdx.x * 96;

  int wi = 0, nb = n0;
  const u16* BT = Bq;
  if (MODE == 0) {
    wi = n0 / DIM;
    nb = n0 - wi * DIM;
    BT = (wi == 0) ? Bq : (wi == 1) ? Bk : Bv;
  }

  const int sr8 = lane >> 3;              // row within 8-row staging slab
  const int sc  = ((lane & 7) ^ sr8) * 8; // swizzled source chunk (u16)
  const int key = (l16 & 7);              // read-side swizzle key

  f32x4 acc[MT][3] = {};

  for (int k0 = 0; k0 < DIM; k0 += 64) {
    __syncthreads();
#pragma unroll
    for (int j = 0; j < MT; ++j)
      gload_lds16(A + (size_t)(m0 + wv * (BM / 4) + j * 8 + sr8) * DIM + k0 + sc,
                  &Al[(wv * (BM / 4) + j * 8) * 64]);
#pragma unroll
    for (int j = 0; j < 3; ++j)
      gload_lds16(BT + (size_t)(nb + wv * 24 + j * 8 + sr8) * DIM + k0 + sc,
                  &Bl[(wv * 24 + j * 8) * 64]);
    __syncthreads();

#pragma unroll
    for (int kh = 0; kh < 2; ++kh) {
      const int cb = kh * 4;
      bf16x8 af[MT], bfr[3];
#pragma unroll
      for (int mt = 0; mt < MT; ++mt) {
        const int row = wr * (BM / 2) + mt * 16 + l16;
        af[mt] = *(const bf16x8*)&Al[row * 64 + ((cb + quad) ^ key) * 8];
      }
#pragma unroll
      for (int nt = 0; nt < 3; ++nt) {
        const int row = wc * 48 + nt * 16 + l16;
        bfr[nt] = *(const bf16x8*)&Bl[row * 64 + ((cb + quad) ^ key) * 8];
      }
#pragma unroll
      for (int mt = 0; mt < MT; ++mt)
#pragma unroll
        for (int nt = 0; nt < 3; ++nt)
          acc[mt][nt] = __builtin_amdgcn_mfma_f32_16x16x32_bf16(
              af[mt], bfr[nt], acc[mt][nt], 0, 0, 0);
    }
  }

  const float sc_out = (MODE == 0 && wi == 0) ? QSCALE : 1.0f;
#pragma unroll
  for (int mt = 0; mt < MT; ++mt) {
#pragma unroll
    for (int nt = 0; nt < 3; ++nt) {
      const int row = m0 + wr * (BM / 2) + mt * 16 + quad * 4;
      const int nc  = wc * 48 + nt * 16 + l16;
      if (MODE == 0) {
        const int ncol = nb + nc;
        if (wi < 2) {
          u16* dst = (wi == 0) ? Qb : Kb;
#pragma unroll
          for (int r = 0; r < 4; ++r)
            dst[(size_t)(row + r) * DIM + ncol] = f2bf(acc[mt][nt][r] * sc_out);
        } else {
          u16 pk[4];
#pragma unroll
          for (int r = 0; r < 4; ++r) pk[r] = f2bf(acc[mt][nt][r]);
          unsigned long long v;
          __builtin_memcpy(&v, pk, 8);
          *(unsigned long long*)(VT + (size_t)ncol * S_LEN + row) = v;
        }
      } else {
        const int ncol = n0 + nc;
        const float bvv = bias[ncol];
#pragma unroll
        for (int r = 0; r < 4; ++r)
          Out[(size_t)(row + r) * DIM + ncol] = acc[mt][nt][r] + bvv;
      }
    }
  }
}

// ---------------------------------------------------------------------------
// Flash causal attention. 768 blocks x 256 thr (4 waves), 3 blocks/CU.
// Block handles q-tiles qt=bx (rows 32bx..+31) and qt=127-bx. Wave w owns
// 16 q-rows: w<2 -> side A, w>=2 -> side B. kv loop over 64-wide tiles up to
// side B's diagonal; side-A waves go idle past their own diagonal (block
// wall-time ~ nktB, longest-first dispatch order per XCD -> LPT balance).
// K/V double-buffered; ONE barrier per tile; prefetch overlaps compute.
// Fixed-max softmax (Q pre-scaled by 0.125*log2e in projection).
__global__ __launch_bounds__(256)
void attn_mfma_kernel(const u16* __restrict__ Qb, const u16* __restrict__ Kb,
                      const u16* __restrict__ VTb, u16* __restrict__ ctx) {
  __shared__ __align__(16) u16 Ql[64 * 72];     // rows 0..31 A, 32..63 B
  __shared__ __align__(16) u16 Kl[2][64 * 64];  // [buf][kv][d] swizzled
  __shared__ __align__(16) u16 Vl[2][64 * 64];  // [buf][d][kv] swizzled
  __shared__ __align__(16) u16 Pl[4][16 * 72];  // per-wave P

  const int tid  = threadIdx.x;
  const int w    = tid >> 6;
  const int lane = tid & 63;
  const int quad = lane >> 4;
  const int l16  = lane & 15;
  const int key  = l16 & 7;

  // XCD-aware (head, pair) mapping: residue class id&7 hosts head id&7
  // (slots 0..63) plus half of head 8+((id&7)>>1) (slots 64..95).
  // Primary slots ascend bx -> descending work (nktB = 64-bx/2): LPT order.
  const int id = blockIdx.x;
  const int rc = id & 7, slot = id >> 3;
  const int h  = (slot < 64) ? rc : 8 + (rc >> 1);
  const int bx = (slot < 64) ? slot : ((rc & 1) * 32 + (slot - 64));

  const int q0A = bx * 32;
  const int q0B = (127 - bx) * 32;
  const int qlo = ((w < 2) ? q0A : q0B) + (w & 1) * 16;  // wave's first q-row
  const int nkt_w = ((qlo + 15) >> 6) + 1;               // wave's tile count
  const int nktB  = ((q0B + 31) >> 6) + 1;               // block tile count

  // Staging: wave w stages K rows w*16..+15 and V d-rows w*16..+15 (2 gloads
  // each). Source col swizzled by row&7 (= sr8 since rows are 8-aligned).
  const int sr8 = lane >> 3;               // row-in-8-slab
  const int sc  = ((lane & 7) ^ sr8) * 8;  // swizzled source chunk

  // Stage Ql (64 rows x 64 d, pitch 72).
  {
    const int qrow_s = tid >> 3;           // 0..31
    const int qcol_s = (tid & 7) * 8;
    *(bf16x8*)&Ql[qrow_s * 72 + qcol_s] =
        *(const bf16x8*)(Qb + (size_t)(q0A + qrow_s) * DIM + h * 64 + qcol_s);
    *(bf16x8*)&Ql[(32 + qrow_s) * 72 + qcol_s] =
        *(const bf16x8*)(Qb + (size_t)(q0B + qrow_s) * DIM + h * 64 + qcol_s);
  }
  // Prefetch tile 0 into buffer 0.
#pragma unroll
  for (int j = 0; j < 2; ++j) {
    gload_lds16(Kb + (size_t)(w * 16 + j * 8 + sr8) * DIM + h * 64 + sc,
                &Kl[0][(w * 16 + j * 8) * 64]);
    gload_lds16(VTb + (size_t)(h * 64 + w * 16 + j * 8 + sr8) * S_LEN + sc,
                &Vl[0][(w * 16 + j * 8) * 64]);
  }
  __syncthreads();  // Ql visible (vmcnt also drains tile 0 — once per block)

  // Q fragments hoisted to registers.
  const bf16x8 aq0 = *(const bf16x8*)&Ql[(w * 16 + l16) * 72 + quad * 8];
  const bf16x8 aq1 = *(const bf16x8*)&Ql[(w * 16 + l16) * 72 + 32 + quad * 8];

  f32x4 o[4] = {};
  float l_r[4] = {};

#pragma unroll 1
  for (int kt = 0; kt < nktB; ++kt) {
    __syncthreads();  // tile kt's staging drained; prior readers done
    const int b = kt & 1;

    // Prefetch tile kt+1 into the other buffer (overlaps compute below).
    if (kt + 1 < nktB) {
      const int kn = (kt + 1) * 64;
#pragma unroll
      for (int j = 0; j < 2; ++j) {
        gload_lds16(Kb + (size_t)(kn + w * 16 + j * 8 + sr8) * DIM + h * 64 + sc,
                    &Kl[b ^ 1][(w * 16 + j * 8) * 64]);
        gload_lds16(VTb + (size_t)(h * 64 + w * 16 + j * 8 + sr8) * S_LEN + kn + sc,
                    &Vl[b ^ 1][(w * 16 + j * 8) * 64]);
      }
    }

    if (kt < nkt_w) {
      const int k0 = kt * 64;
      // S = Q K^T : 16 q-rows x 64 kv
      f32x4 s[4];
#pragma unroll
      for (int t = 0; t < 4; ++t) {
        const int row = t * 16 + l16;
        const bf16x8 bk0 = *(const bf16x8*)&Kl[b][row * 64 + (quad ^ key) * 8];
        const bf16x8 bk1 = *(const bf16x8*)&Kl[b][row * 64 + ((quad ^ 4) ^ key) * 8];
        s[t] = __builtin_amdgcn_mfma_f32_16x16x32_bf16(
            aq0, bk0, f32x4{0.f, 0.f, 0.f, 0.f}, 0, 0, 0);
        s[t] = __builtin_amdgcn_mfma_f32_16x16x32_bf16(aq1, bk1, s[t], 0, 0, 0);
      }

      // P = 2^S; mask on the wave's diagonal tile.
      if (kt == nkt_w - 1) {
#pragma unroll
        for (int t = 0; t < 4; ++t)
#pragma unroll
          for (int r = 0; r < 4; ++r) {
            const int kvg = k0 + t * 16 + l16;
            const int qg  = qlo + quad * 4 + r;
            float p = __builtin_amdgcn_exp2f(s[t][r]);
            if (kvg > qg) p = 0.f;
            l_r[r] += p;
            Pl[w][(quad * 4 + r) * 72 + t * 16 + l16] =
                (u16)((__float_as_uint(p) + 0x8000u) >> 16);
          }
      } else {
#pragma unroll
        for (int t = 0; t < 4; ++t)
#pragma unroll
          for (int r = 0; r < 4; ++r) {
            const float p = __builtin_amdgcn_exp2f(s[t][r]);
            l_r[r] += p;
            Pl[w][(quad * 4 + r) * 72 + t * 16 + l16] =
                (u16)((__float_as_uint(p) + 0x8000u) >> 16);
          }
      }

      // O += P V (in-wave Pl write->read ordered by lgkmcnt)
      const bf16x8 pa0 = *(const bf16x8*)&Pl[w][l16 * 72 + quad * 8];
      const bf16x8 pa1 = *(const bf16x8*)&Pl[w][l16 * 72 + 32 + quad * 8];
#pragma unroll
      for (int t = 0; t < 4; ++t) {
        const int row = t * 16 + l16;  // d-row in Vl
        const bf16x8 vb0 = *(const bf16x8*)&Vl[b][row * 64 + (quad ^ key) * 8];
        const bf16x8 vb1 = *(const bf16x8*)&Vl[b][row * 64 + ((quad ^ 4) ^ key) * 8];
        o[t] = __builtin_amdgcn_mfma_f32_16x16x32_bf16(pa0, vb0, o[t], 0, 0, 0);
        o[t] = __builtin_amdgcn_mfma_f32_16x16x32_bf16(pa1, vb1, o[t], 0, 0, 0);
      }
    }
  }

  // Epilogue: each wave owns its 16 q-rows outright (no combine).
#pragma unroll
  for (int r = 0; r < 4; ++r) {
    float l = l_r[r];
    l += __shfl_xor(l, 1);
    l += __shfl_xor(l, 2);
    l += __shfl_xor(l, 4);
    l += __shfl_xor(l, 8);
    const float inv = 1.f / l;
    const int row = qlo + quad * 4 + r;
#pragma unroll
    for (int t = 0; t < 4; ++t)
      ctx[(size_t)row * DIM + h * 64 + t * 16 + l16] = f2bf(o[t][r] * inv);
  }
}

// ---------------------------------------------------------------------------
extern "C" void kernel_launch(void* const* d_in, const int* in_sizes, int n_in,
                              void* d_out, int out_size, void* d_ws,
                              size_t ws_size, hipStream_t stream) {
  const float* x  = (const float*)d_in[0];
  const float* wq = (const float*)d_in[1];
  const float* wk = (const float*)d_in[2];
  const float* wv = (const float*)d_in[3];
  const float* wo = (const float*)d_in[4];
  const float* bo = (const float*)d_in[5];

  const size_t n_x = (size_t)S_LEN * DIM;
  const size_t n_w = (size_t)DIM * DIM;
  u16* xb  = (u16*)d_ws;
  u16* wtq = xb + n_x;
  u16* wtk = wtq + n_w;
  u16* wtv = wtk + n_w;
  u16* wto = wtv + n_w;
  u16* Qb  = wto + n_w;
  u16* Kb  = Qb + n_x;
  u16* VTb = Kb + n_x;   // [768][4096]
  u16* ctx = VTb + n_x;

  prep_kernel<<<dim3(12, 12, 5), 256, 0, stream>>>(
      x, wq, wk, wv, wo, xb, wtq, wtk, wtv, wto);

  // Fused QKV: N = 3*768, 128x96 tiles -> 24x32 = 768 blocks (3/CU exact).
  mfma_gemm_kernel<0><<<dim3(24, 32), 256, 0, stream>>>(
      xb, wtq, wtk, wtv, nullptr, Qb, Kb, VTb, nullptr);

  attn_mfma_kernel<<<dim3(768), 256, 0, stream>>>(Qb, Kb, VTb, ctx);

  // Output GEMM: 64x96 tiles -> 8x64 = 512 blocks (2/CU exact), fp32 + bias.
  mfma_gemm_kernel<1><<<dim3(8, 64), 256, 0, stream>>>(
      ctx, wto, nullptr, nullptr, bo, nullptr, nullptr, nullptr, (float*)d_out);
}

// Round 11
// 178.935 us; speedup vs baseline: 1.0816x; 1.0816x over previous
//
#include <hip/hip_runtime.h>

// MultiHeadAttention: B=1, S=4096, D=768, H=12, HD=64, causal, fp32 in/out.
// Round 10: attn = R8 verbatim (75 µs best; kv-split duty > barrier count,
// R9 post-mortem). GEMMs: C^T-via-swapped-MFMA epilogue -> packed stores
// (Q/K: 12x8B instead of 48x2B per thread; out: 6x16B float4). V path keeps
// normal orientation (already packed). Prep unchanged.

typedef short bf16x8 __attribute__((ext_vector_type(8)));
typedef float f32x4 __attribute__((ext_vector_type(4)));
typedef unsigned short u16;

static constexpr int S_LEN = 4096;
static constexpr int DIM   = 768;
static constexpr int NH    = 12;
// softmax scale folded into Q projection: 1/sqrt(64) * log2(e)
static constexpr float QSCALE = 0.125f * 1.44269504088896340736f;

__device__ inline u16 f2bf(float f) {
  union { float f; unsigned int u; } v; v.f = f;
  unsigned int r = v.u + 0x7FFFu + ((v.u >> 16) & 1u);  // RNE
  return (u16)(r >> 16);
}

__device__ inline void gload_lds16(const u16* g, u16* s) {
  __builtin_amdgcn_global_load_lds(
      (const __attribute__((address_space(1))) unsigned int*)g,
      (__attribute__((address_space(3))) unsigned int*)s, 16, 0, 0);
}

// ---------------------------------------------------------------------------
// Prep: z<4 -> transpose W[z] fp32 -> bf16 W^T; z==4 -> convert x -> bf16.
__global__ __launch_bounds__(256)
void prep_kernel(const float* __restrict__ x, const float* __restrict__ w0,
                 const float* __restrict__ w1, const float* __restrict__ w2,
                 const float* __restrict__ w3, u16* __restrict__ xb,
                 u16* __restrict__ t0, u16* __restrict__ t1,
                 u16* __restrict__ t2, u16* __restrict__ t3) {
  if (blockIdx.z == 4) {
    const size_t n = (size_t)S_LEN * DIM;
    const int id = blockIdx.y * 12 + blockIdx.x;
    const size_t stride = (size_t)144 * 256 * 8;
    for (size_t i = ((size_t)id * 256 + threadIdx.x) * 8; i < n; i += stride) {
      const float4 a = *(const float4*)(x + i);
      const float4 b = *(const float4*)(x + i + 4);
      bf16x8 o;
      o[0] = (short)f2bf(a.x); o[1] = (short)f2bf(a.y);
      o[2] = (short)f2bf(a.z); o[3] = (short)f2bf(a.w);
      o[4] = (short)f2bf(b.x); o[5] = (short)f2bf(b.y);
      o[6] = (short)f2bf(b.z); o[7] = (short)f2bf(b.w);
      *(bf16x8*)(xb + i) = o;
    }
    return;
  }
  __shared__ float T[64][65];
  const float* src; u16* dst;
  switch (blockIdx.z) {
    case 0: src = w0; dst = t0; break;
    case 1: src = w1; dst = t1; break;
    case 2: src = w2; dst = t2; break;
    default: src = w3; dst = t3; break;
  }
  const int k0 = blockIdx.y * 64, n0 = blockIdx.x * 64;
  const int r = threadIdx.x >> 2, c0 = (threadIdx.x & 3) * 16;
#pragma unroll
  for (int i = 0; i < 4; ++i) {
    const float4 v = *(const float4*)(src + (size_t)(k0 + r) * DIM + n0 + c0 + i * 4);
    T[r][c0 + i * 4 + 0] = v.x;
    T[r][c0 + i * 4 + 1] = v.y;
    T[r][c0 + i * 4 + 2] = v.z;
    T[r][c0 + i * 4 + 3] = v.w;
  }
  __syncthreads();
  bf16x8 o0, o1;
#pragma unroll
  for (int i = 0; i < 8; ++i) {
    o0[i] = (short)f2bf(T[c0 + i][r]);
    o1[i] = (short)f2bf(T[c0 + 8 + i][r]);
  }
  *(bf16x8*)(dst + (size_t)(n0 + r) * DIM + k0 + c0) = o0;
  *(bf16x8*)(dst + (size_t)(n0 + r) * DIM + k0 + c0 + 8) = o1;
}

// ---------------------------------------------------------------------------
// MFMA GEMM, BK=64, BN=96, global_load_lds staging with XOR chunk swizzle.
// MODE 0: fused QKV (BM=128, grid 24x32). wi = n0/768: Q (scaled), K
//         row-major bf16 via SWAPPED mfma (C^T frag -> packed 8B stores);
//         V -> VT[768][4096] via normal orientation (already packed).
// MODE 1: out GEMM (BM=64, grid 8x64), fp32 + bias, swapped -> float4 stores.
template <int MODE>
__global__ __launch_bounds__(256)
void mfma_gemm_kernel(const u16* __restrict__ A, const u16* __restrict__ Bq,
                      const u16* __restrict__ Bk, const u16* __restrict__ Bv,
                      const float* __restrict__ bias, u16* __restrict__ Qb,
                      u16* __restrict__ Kb, u16* __restrict__ VT,
                      float* __restrict__ Out) {
  constexpr int MT = (MODE == 0) ? 4 : 2;   // m-frags (16) per wave
  constexpr int BM = MT * 32;
  __shared__ __align__(16) u16 Al[BM * 64];
  __shared__ __align__(16) u16 Bl[96 * 64];

  const int tid  = threadIdx.x;
  const int wv   = tid >> 6;
  const int lane = tid & 63;
  const int quad = lane >> 4;
  const int l16  = lane & 15;
  const int wr = wv >> 1, wc = wv & 1;
  const int m0 = blockIdx.y * BM;
  const int n0 = blockIdx.x * 96;

  int wi = 0, nb = n0;
  const u16* BT = Bq;
  if (MODE == 0) {
    wi = n0 / DIM;
    nb = n0 - wi * DIM;
    BT = (wi == 0) ? Bq : (wi == 1) ? Bk : Bv;
  }

  const int sr8 = lane >> 3;              // row within 8-row staging slab
  const int sc  = ((lane & 7) ^ sr8) * 8; // swizzled source chunk (u16)
  const int key = (l16 & 15) & 7;         // read-side swizzle key

  const bool swp = (MODE == 1) || (wi < 2);  // uniform per block

  f32x4 acc[MT][3] = {};

  for (int k0 = 0; k0 < DIM; k0 += 64) {
    __syncthreads();
#pragma unroll
    for (int j = 0; j < MT; ++j)
      gload_lds16(A + (size_t)(m0 + wv * (BM / 4) + j * 8 + sr8) * DIM + k0 + sc,
                  &Al[(wv * (BM / 4) + j * 8) * 64]);
#pragma unroll
    for (int j = 0; j < 3; ++j)
      gload_lds16(BT + (size_t)(nb + wv * 24 + j * 8 + sr8) * DIM + k0 + sc,
                  &Bl[(wv * 24 + j * 8) * 64]);
    __syncthreads();

#pragma unroll
    for (int kh = 0; kh < 2; ++kh) {
      const int cb = kh * 4;
      bf16x8 af[MT], bfr[3];
#pragma unroll
      for (int mt = 0; mt < MT; ++mt) {
        const int row = wr * (BM / 2) + mt * 16 + l16;
        af[mt] = *(const bf16x8*)&Al[row * 64 + ((cb + quad) ^ key) * 8];
      }
#pragma unroll
      for (int nt = 0; nt < 3; ++nt) {
        const int row = wc * 48 + nt * 16 + l16;
        bfr[nt] = *(const bf16x8*)&Bl[row * 64 + ((cb + quad) ^ key) * 8];
      }
      if (swp) {
        // C^T: D = Bfrag x Afrag -> lane holds row m=l16, cols n=quad*4+r.
#pragma unroll
        for (int mt = 0; mt < MT; ++mt)
#pragma unroll
          for (int nt = 0; nt < 3; ++nt)
            acc[mt][nt] = __builtin_amdgcn_mfma_f32_16x16x32_bf16(
                bfr[nt], af[mt], acc[mt][nt], 0, 0, 0);
      } else {
#pragma unroll
        for (int mt = 0; mt < MT; ++mt)
#pragma unroll
          for (int nt = 0; nt < 3; ++nt)
            acc[mt][nt] = __builtin_amdgcn_mfma_f32_16x16x32_bf16(
                af[mt], bfr[nt], acc[mt][nt], 0, 0, 0);
      }
    }
  }

  if (MODE == 0 && wi >= 2) {
    // V path (normal orientation): lane holds col=l16, rows quad*4+r.
#pragma unroll
    for (int mt = 0; mt < MT; ++mt) {
#pragma unroll
      for (int nt = 0; nt < 3; ++nt) {
        const int row  = m0 + wr * (BM / 2) + mt * 16 + quad * 4;
        const int ncol = nb + wc * 48 + nt * 16 + l16;
        u16 pk[4];
#pragma unroll
        for (int r = 0; r < 4; ++r) pk[r] = f2bf(acc[mt][nt][r]);
        unsigned long long v;
        __builtin_memcpy(&v, pk, 8);
        *(unsigned long long*)(VT + (size_t)ncol * S_LEN + row) = v;
      }
    }
  } else if (MODE == 0) {
    // Q/K path (swapped): packed 8B row-major stores.
    u16* dst = (wi == 0) ? Qb : Kb;
    const float sc_out = (wi == 0) ? QSCALE : 1.0f;
#pragma unroll
    for (int mt = 0; mt < MT; ++mt) {
#pragma unroll
      for (int nt = 0; nt < 3; ++nt) {
        const int row = m0 + wr * (BM / 2) + mt * 16 + l16;
        const int ncb = nb + wc * 48 + nt * 16 + quad * 4;
        u16 pk[4];
#pragma unroll
        for (int r = 0; r < 4; ++r) pk[r] = f2bf(acc[mt][nt][r] * sc_out);
        unsigned long long v;
        __builtin_memcpy(&v, pk, 8);
        *(unsigned long long*)(dst + (size_t)row * DIM + ncb) = v;
      }
    }
  } else {
    // Out GEMM (swapped): float4 stores + float4 bias loads.
#pragma unroll
    for (int mt = 0; mt < MT; ++mt) {
#pragma unroll
      for (int nt = 0; nt < 3; ++nt) {
        const int row = m0 + wr * (BM / 2) + mt * 16 + l16;
        const int ncb = n0 + wc * 48 + nt * 16 + quad * 4;
        const float4 b4 = *(const float4*)(bias + ncb);
        float4 ov;
        ov.x = acc[mt][nt][0] + b4.x;
        ov.y = acc[mt][nt][1] + b4.y;
        ov.z = acc[mt][nt][2] + b4.z;
        ov.w = acc[mt][nt][3] + b4.w;
        *(float4*)(Out + (size_t)row * DIM + ncb) = ov;
      }
    }
  }
}

// ---------------------------------------------------------------------------
// Flash causal attention — R8/R3 measured-best kernel (75 µs), verbatim.
// 768 blocks x 256 thr (4 waves). Wave w: q-subtile qw=w>>1, kv-half kw=w&1.
// Per iteration a 128-wide kv slab staged via global_load_lds; fixed-max
// softmax (Q pre-scaled by 0.125*log2e); kv-halves combine via LDS exchange.
__global__ __launch_bounds__(256)
void attn_mfma_kernel(const u16* __restrict__ Qb, const u16* __restrict__ Kb,
                      const u16* __restrict__ VTb, u16* __restrict__ ctx) {
  __shared__ __align__(16) u16 Ql[32 * 72];
  __shared__ __align__(16) u16 Kl[128 * 64];   // [kv][d] swizzled; Obuf reuse
  __shared__ __align__(16) u16 Vl[64 * 128];   // [d][kv] swizzled
  __shared__ __align__(16) u16 Pl[4][16 * 72];
  __shared__ float4 lbuf[4][64];

  const int tid  = threadIdx.x;
  const int w    = tid >> 6;
  const int lane = tid & 63;
  const int quad = lane >> 4;
  const int l16  = lane & 15;
  const int qw   = w >> 1;
  const int kw   = w & 1;
  const int key  = l16 & 7;

  // XCD-aware (head, pair) mapping: residue class id&7 hosts head id&7
  // (slots 0..63) plus half of head 8+((id&7)>>1) (slots 64..95).
  const int id = blockIdx.x;
  const int rc = id & 7, slot = id >> 3;
  const int h  = (slot < 64) ? rc : 8 + (rc >> 1);
  const int bx = (slot < 64) ? slot : ((rc & 1) * 32 + (slot - 64));

  const int sr8  = lane >> 3;               // K: row-in-slab
  const int scK  = ((lane & 7) ^ sr8) * 8;  // K: swizzled source col
  const int sr16 = lane >> 4;               // V: row-in-slab

#pragma unroll 1
  for (int side = 0; side < 2; ++side) {
    const int qt = side ? (127 - bx) : bx;
    const int q0 = qt * 32;

    __syncthreads();
    {
      const int row = tid >> 3, col = (tid & 7) * 8;
      *(bf16x8*)&Ql[row * 72 + col] =
          *(const bf16x8*)(Qb + (size_t)(q0 + row) * DIM + h * 64 + col);
    }

    f32x4 o[4] = {};
    float l_r[4] = {};

    const int nkt = qt / 2 + 1;          // 64-wide k-tiles
    const int niter = (nkt + 1) >> 1;    // 128-wide slabs
    const int my_last = nkt - 1;         // diagonal tile index

#pragma unroll 1
    for (int i = 0; i < niter; ++i) {
      const int k0g = i * 128;
      __syncthreads();  // all waves done reading Kl/Vl (and Obuf last side)
#pragma unroll
      for (int j = 0; j < 4; ++j)
        gload_lds16(Kb + (size_t)(k0g + w * 32 + j * 8 + sr8) * DIM + h * 64 + scK,
                    &Kl[(w * 32 + j * 8) * 64]);
#pragma unroll
      for (int j = 0; j < 4; ++j) {
        const int vrow = w * 16 + j * 4 + sr16;
        const int vcol = ((lane & 15) ^ (vrow & 7)) * 8;
        gload_lds16(VTb + (size_t)(h * 64 + vrow) * S_LEN + k0g + vcol,
                    &Vl[(w * 16 + j * 4) * 128]);
      }
      __syncthreads();

      const int kt_w = 2 * i + kw;
      if (kt_w < nkt) {
        // S = Q K^T : 16 q-rows x 64 kv (this wave's half)
        const bf16x8 aq0 = *(const bf16x8*)&Ql[(qw * 16 + l16) * 72 + quad * 8];
        const bf16x8 aq1 = *(const bf16x8*)&Ql[(qw * 16 + l16) * 72 + 32 + quad * 8];
        f32x4 s[4];
#pragma unroll
        for (int t = 0; t < 4; ++t) {
          const int row = kw * 64 + t * 16 + l16;
          const bf16x8 bk0 = *(const bf16x8*)&Kl[row * 64 + (quad ^ key) * 8];
          const bf16x8 bk1 = *(const bf16x8*)&Kl[row * 64 + ((quad ^ 4) ^ key) * 8];
          s[t] = __builtin_amdgcn_mfma_f32_16x16x32_bf16(aq0, bk0, f32x4{0.f,0.f,0.f,0.f}, 0, 0, 0);
          s[t] = __builtin_amdgcn_mfma_f32_16x16x32_bf16(aq1, bk1, s[t], 0, 0, 0);
        }

        // P = 2^S; mask on diagonal tile.
        if (kt_w == my_last) {
#pragma unroll
          for (int t = 0; t < 4; ++t)
#pragma unroll
            for (int r = 0; r < 4; ++r) {
              const int kvg = k0g + kw * 64 + t * 16 + l16;
              const int qg  = q0 + qw * 16 + quad * 4 + r;
              float p = __builtin_amdgcn_exp2f(s[t][r]);
              if (kvg > qg) p = 0.f;
              l_r[r] += p;
              Pl[w][(quad * 4 + r) * 72 + t * 16 + l16] =
                  (u16)((__float_as_uint(p) + 0x8000u) >> 16);
            }
        } else {
#pragma unroll
          for (int t = 0; t < 4; ++t)
#pragma unroll
            for (int r = 0; r < 4; ++r) {
              const float p = __builtin_amdgcn_exp2f(s[t][r]);
              l_r[r] += p;
              Pl[w][(quad * 4 + r) * 72 + t * 16 + l16] =
                  (u16)((__float_as_uint(p) + 0x8000u) >> 16);
            }
        }

        // O += P V (in-wave Pl write->read ordered by lgkmcnt)
        const bf16x8 pa0 = *(const bf16x8*)&Pl[w][l16 * 72 + quad * 8];
        const bf16x8 pa1 = *(const bf16x8*)&Pl[w][l16 * 72 + 32 + quad * 8];
#pragma unroll
        for (int t = 0; t < 4; ++t) {
          const int row = t * 16 + l16;  // d-row in Vl
          const int c0 = (kw * 8 + quad) ^ key;
          const int c1 = (kw * 8 + quad + 4) ^ key;
          const bf16x8 vb0 = *(const bf16x8*)&Vl[row * 128 + c0 * 8];
          const bf16x8 vb1 = *(const bf16x8*)&Vl[row * 128 + c1 * 8];
          o[t] = __builtin_amdgcn_mfma_f32_16x16x32_bf16(pa0, vb0, o[t], 0, 0, 0);
          o[t] = __builtin_amdgcn_mfma_f32_16x16x32_bf16(pa1, vb1, o[t], 0, 0, 0);
        }
      }
    }

    // Combine kv-halves: waves w and w^1 hold partials for the same q-rows.
    __syncthreads();  // all waves done with Kl/Vl reads before Obuf reuse
    float* Obuf = (float*)Kl;  // 4 waves x 64 lanes x 16 floats = 16 KB
#pragma unroll
    for (int t = 0; t < 4; ++t)
      *(f32x4*)&Obuf[(w * 64 + lane) * 16 + t * 4] = o[t];
    lbuf[w][lane] = float4{l_r[0], l_r[1], l_r[2], l_r[3]};
    __syncthreads();
#pragma unroll
    for (int t = 0; t < 4; ++t) {
      const f32x4 po = *(const f32x4*)&Obuf[((w ^ 1) * 64 + lane) * 16 + t * 4];
      o[t] += po;
    }
    {
      const float4 pl = lbuf[w ^ 1][lane];
      l_r[0] += pl.x; l_r[1] += pl.y; l_r[2] += pl.z; l_r[3] += pl.w;
    }

    if (kw == 0) {
#pragma unroll
      for (int r = 0; r < 4; ++r) {
        float l = l_r[r];
        l += __shfl_xor(l, 1);
        l += __shfl_xor(l, 2);
        l += __shfl_xor(l, 4);
        l += __shfl_xor(l, 8);
        const float inv = 1.f / l;
        const int row = q0 + qw * 16 + quad * 4 + r;
#pragma unroll
        for (int t = 0; t < 4; ++t)
          ctx[(size_t)row * DIM + h * 64 + t * 16 + l16] = f2bf(o[t][r] * inv);
      }
    }
  }
}

// ---------------------------------------------------------------------------
extern "C" void kernel_launch(void* const* d_in, const int* in_sizes, int n_in,
                              void* d_out, int out_size, void* d_ws,
                              size_t ws_size, hipStream_t stream) {
  const float* x  = (const float*)d_in[0];
  const float* wq = (const float*)d_in[1];
  const float* wk = (const float*)d_in[2];
  const float* wv = (const float*)d_in[3];
  const float* wo = (const float*)d_in[4];
  const float* bo = (const float*)d_in[5];

  const size_t n_x = (size_t)S_LEN * DIM;
  const size_t n_w = (size_t)DIM * DIM;
  u16* xb  = (u16*)d_ws;
  u16* wtq = xb + n_x;
  u16* wtk = wtq + n_w;
  u16* wtv = wtk + n_w;
  u16* wto = wtv + n_w;
  u16* Qb  = wto + n_w;
  u16* Kb  = Qb + n_x;
  u16* VTb = Kb + n_x;   // [768][4096]
  u16* ctx = VTb + n_x;

  prep_kernel<<<dim3(12, 12, 5), 256, 0, stream>>>(
      x, wq, wk, wv, wo, xb, wtq, wtk, wtv, wto);

  // Fused QKV: N = 3*768, 128x96 tiles -> 24x32 = 768 blocks (3/CU exact).
  mfma_gemm_kernel<0><<<dim3(24, 32), 256, 0, stream>>>(
      xb, wtq, wtk, wtv, nullptr, Qb, Kb, VTb, nullptr);

  attn_mfma_kernel<<<dim3(768), 256, 0, stream>>>(Qb, Kb, VTb, ctx);

  // Output GEMM: 64x96 tiles -> 8x64 = 512 blocks (2/CU exact), fp32 + bias.
  mfma_gemm_kernel<1><<<dim3(8, 64), 256, 0, stream>>>(
      ctx, wto, nullptr, nullptr, bo, nullptr, nullptr, nullptr, (float*)d_out);
}

// Round 12
// 174.462 us; speedup vs baseline: 1.1093x; 1.0256x over previous
//
#include <hip/hip_runtime.h>

// MultiHeadAttention: B=1, S=4096, D=768, H=12, HD=64, causal, fp32 in/out.
// Round 11: attn trims on the R8 structure: (1) combine Obuf stride 16->20
// floats (fixes 4x bank-conflict hotspot: stride-16 starts hit only banks
// {0,16}); (2) Q fragments in registers (Ql LDS + staging + 2 ds_reads/slab
// deleted; safe per R9, unlike R7's K/V prefetch spill); (3) one fewer
// barrier per side. GEMMs/prep = R10 (packed C^T epilogues).

typedef short bf16x8 __attribute__((ext_vector_type(8)));
typedef float f32x4 __attribute__((ext_vector_type(4)));
typedef unsigned short u16;

static constexpr int S_LEN = 4096;
static constexpr int DIM   = 768;
static constexpr int NH    = 12;
// softmax scale folded into Q projection: 1/sqrt(64) * log2(e)
static constexpr float QSCALE = 0.125f * 1.44269504088896340736f;

__device__ inline u16 f2bf(float f) {
  union { float f; unsigned int u; } v; v.f = f;
  unsigned int r = v.u + 0x7FFFu + ((v.u >> 16) & 1u);  // RNE
  return (u16)(r >> 16);
}

__device__ inline void gload_lds16(const u16* g, u16* s) {
  __builtin_amdgcn_global_load_lds(
      (const __attribute__((address_space(1))) unsigned int*)g,
      (__attribute__((address_space(3))) unsigned int*)s, 16, 0, 0);
}

// ---------------------------------------------------------------------------
// Prep: z<4 -> transpose W[z] fp32 -> bf16 W^T; z==4 -> convert x -> bf16.
__global__ __launch_bounds__(256)
void prep_kernel(const float* __restrict__ x, const float* __restrict__ w0,
                 const float* __restrict__ w1, const float* __restrict__ w2,
                 const float* __restrict__ w3, u16* __restrict__ xb,
                 u16* __restrict__ t0, u16* __restrict__ t1,
                 u16* __restrict__ t2, u16* __restrict__ t3) {
  if (blockIdx.z == 4) {
    const size_t n = (size_t)S_LEN * DIM;
    const int id = blockIdx.y * 12 + blockIdx.x;
    const size_t stride = (size_t)144 * 256 * 8;
    for (size_t i = ((size_t)id * 256 + threadIdx.x) * 8; i < n; i += stride) {
      const float4 a = *(const float4*)(x + i);
      const float4 b = *(const float4*)(x + i + 4);
      bf16x8 o;
      o[0] = (short)f2bf(a.x); o[1] = (short)f2bf(a.y);
      o[2] = (short)f2bf(a.z); o[3] = (short)f2bf(a.w);
      o[4] = (short)f2bf(b.x); o[5] = (short)f2bf(b.y);
      o[6] = (short)f2bf(b.z); o[7] = (short)f2bf(b.w);
      *(bf16x8*)(xb + i) = o;
    }
    return;
  }
  __shared__ float T[64][65];
  const float* src; u16* dst;
  switch (blockIdx.z) {
    case 0: src = w0; dst = t0; break;
    case 1: src = w1; dst = t1; break;
    case 2: src = w2; dst = t2; break;
    default: src = w3; dst = t3; break;
  }
  const int k0 = blockIdx.y * 64, n0 = blockIdx.x * 64;
  const int r = threadIdx.x >> 2, c0 = (threadIdx.x & 3) * 16;
#pragma unroll
  for (int i = 0; i < 4; ++i) {
    const float4 v = *(const float4*)(src + (size_t)(k0 + r) * DIM + n0 + c0 + i * 4);
    T[r][c0 + i * 4 + 0] = v.x;
    T[r][c0 + i * 4 + 1] = v.y;
    T[r][c0 + i * 4 + 2] = v.z;
    T[r][c0 + i * 4 + 3] = v.w;
  }
  __syncthreads();
  bf16x8 o0, o1;
#pragma unroll
  for (int i = 0; i < 8; ++i) {
    o0[i] = (short)f2bf(T[c0 + i][r]);
    o1[i] = (short)f2bf(T[c0 + 8 + i][r]);
  }
  *(bf16x8*)(dst + (size_t)(n0 + r) * DIM + k0 + c0) = o0;
  *(bf16x8*)(dst + (size_t)(n0 + r) * DIM + k0 + c0 + 8) = o1;
}

// ---------------------------------------------------------------------------
// MFMA GEMM, BK=64, BN=96, global_load_lds staging with XOR chunk swizzle.
// MODE 0: fused QKV (BM=128, grid 24x32). wi = n0/768: Q (scaled), K
//         row-major bf16 via SWAPPED mfma (C^T frag -> packed 8B stores);
//         V -> VT[768][4096] via normal orientation (already packed).
// MODE 1: out GEMM (BM=64, grid 8x64), fp32 + bias, swapped -> float4 stores.
template <int MODE>
__global__ __launch_bounds__(256)
void mfma_gemm_kernel(const u16* __restrict__ A, const u16* __restrict__ Bq,
                      const u16* __restrict__ Bk, const u16* __restrict__ Bv,
                      const float* __restrict__ bias, u16* __restrict__ Qb,
                      u16* __restrict__ Kb, u16* __restrict__ VT,
                      float* __restrict__ Out) {
  constexpr int MT = (MODE == 0) ? 4 : 2;   // m-frags (16) per wave
  constexpr int BM = MT * 32;
  __shared__ __align__(16) u16 Al[BM * 64];
  __shared__ __align__(16) u16 Bl[96 * 64];

  const int tid  = threadIdx.x;
  const int wv   = tid >> 6;
  const int lane = tid & 63;
  const int quad = lane >> 4;
  const int l16  = lane & 15;
  const int wr = wv >> 1, wc = wv & 1;
  const int m0 = blockIdx.y * BM;
  const int n0 = blockIdx.x * 96;

  int wi = 0, nb = n0;
  const u16* BT = Bq;
  if (MODE == 0) {
    wi = n0 / DIM;
    nb = n0 - wi * DIM;
    BT = (wi == 0) ? Bq : (wi == 1) ? Bk : Bv;
  }

  const int sr8 = lane >> 3;              // row within 8-row staging slab
  const int sc  = ((lane & 7) ^ sr8) * 8; // swizzled source chunk (u16)
  const int key = l16 & 7;                // read-side swizzle key

  const bool swp = (MODE == 1) || (wi < 2);  // uniform per block

  f32x4 acc[MT][3] = {};

  for (int k0 = 0; k0 < DIM; k0 += 64) {
    __syncthreads();
#pragma unroll
    for (int j = 0; j < MT; ++j)
      gload_lds16(A + (size_t)(m0 + wv * (BM / 4) + j * 8 + sr8) * DIM + k0 + sc,
                  &Al[(wv * (BM / 4) + j * 8) * 64]);
#pragma unroll
    for (int j = 0; j < 3; ++j)
      gload_lds16(BT + (size_t)(nb + wv * 24 + j * 8 + sr8) * DIM + k0 + sc,
                  &Bl[(wv * 24 + j * 8) * 64]);
    __syncthreads();

#pragma unroll
    for (int kh = 0; kh < 2; ++kh) {
      const int cb = kh * 4;
      bf16x8 af[MT], bfr[3];
#pragma unroll
      for (int mt = 0; mt < MT; ++mt) {
        const int row = wr * (BM / 2) + mt * 16 + l16;
        af[mt] = *(const bf16x8*)&Al[row * 64 + ((cb + quad) ^ key) * 8];
      }
#pragma unroll
      for (int nt = 0; nt < 3; ++nt) {
        const int row = wc * 48 + nt * 16 + l16;
        bfr[nt] = *(const bf16x8*)&Bl[row * 64 + ((cb + quad) ^ key) * 8];
      }
      if (swp) {
        // C^T: D = Bfrag x Afrag -> lane holds row m=l16, cols n=quad*4+r.
#pragma unroll
        for (int mt = 0; mt < MT; ++mt)
#pragma unroll
          for (int nt = 0; nt < 3; ++nt)
            acc[mt][nt] = __builtin_amdgcn_mfma_f32_16x16x32_bf16(
                bfr[nt], af[mt], acc[mt][nt], 0, 0, 0);
      } else {
#pragma unroll
        for (int mt = 0; mt < MT; ++mt)
#pragma unroll
          for (int nt = 0; nt < 3; ++nt)
            acc[mt][nt] = __builtin_amdgcn_mfma_f32_16x16x32_bf16(
                af[mt], bfr[nt], acc[mt][nt], 0, 0, 0);
      }
    }
  }

  if (MODE == 0 && wi >= 2) {
    // V path (normal orientation): lane holds col=l16, rows quad*4+r.
#pragma unroll
    for (int mt = 0; mt < MT; ++mt) {
#pragma unroll
      for (int nt = 0; nt < 3; ++nt) {
        const int row  = m0 + wr * (BM / 2) + mt * 16 + quad * 4;
        const int ncol = nb + wc * 48 + nt * 16 + l16;
        u16 pk[4];
#pragma unroll
        for (int r = 0; r < 4; ++r) pk[r] = f2bf(acc[mt][nt][r]);
        unsigned long long v;
        __builtin_memcpy(&v, pk, 8);
        *(unsigned long long*)(VT + (size_t)ncol * S_LEN + row) = v;
      }
    }
  } else if (MODE == 0) {
    // Q/K path (swapped): packed 8B row-major stores.
    u16* dst = (wi == 0) ? Qb : Kb;
    const float sc_out = (wi == 0) ? QSCALE : 1.0f;
#pragma unroll
    for (int mt = 0; mt < MT; ++mt) {
#pragma unroll
      for (int nt = 0; nt < 3; ++nt) {
        const int row = m0 + wr * (BM / 2) + mt * 16 + l16;
        const int ncb = nb + wc * 48 + nt * 16 + quad * 4;
        u16 pk[4];
#pragma unroll
        for (int r = 0; r < 4; ++r) pk[r] = f2bf(acc[mt][nt][r] * sc_out);
        unsigned long long v;
        __builtin_memcpy(&v, pk, 8);
        *(unsigned long long*)(dst + (size_t)row * DIM + ncb) = v;
      }
    }
  } else {
    // Out GEMM (swapped): float4 stores + float4 bias loads.
#pragma unroll
    for (int mt = 0; mt < MT; ++mt) {
#pragma unroll
      for (int nt = 0; nt < 3; ++nt) {
        const int row = m0 + wr * (BM / 2) + mt * 16 + l16;
        const int ncb = n0 + wc * 48 + nt * 16 + quad * 4;
        const float4 b4 = *(const float4*)(bias + ncb);
        float4 ov;
        ov.x = acc[mt][nt][0] + b4.x;
        ov.y = acc[mt][nt][1] + b4.y;
        ov.z = acc[mt][nt][2] + b4.z;
        ov.w = acc[mt][nt][3] + b4.w;
        *(float4*)(Out + (size_t)row * DIM + ncb) = ov;
      }
    }
  }
}

// ---------------------------------------------------------------------------
// Flash causal attention (R8 structure + R11 trims). 768 blocks x 256 thr.
// Wave w: q-subtile qw=w>>1, kv-half kw=w&1. 128-wide kv slabs staged via
// global_load_lds; fixed-max softmax; kv-halves combine via LDS exchange
// with stride-20 Obuf (conflict-free). Q fragments in registers.
__global__ __launch_bounds__(256)
void attn_mfma_kernel(const u16* __restrict__ Qb, const u16* __restrict__ Kb,
                      const u16* __restrict__ VTb, u16* __restrict__ ctx) {
  __shared__ __align__(16) u16 KVl[128 * 64 + 64 * 128];  // Kl | Vl; Obuf reuse
  __shared__ __align__(16) u16 Pl[4][16 * 72];
  __shared__ float4 lbuf[4][64];

  u16* Kl = KVl;                 // [kv][d] swizzled
  u16* Vl = KVl + 128 * 64;      // [d][kv] swizzled

  const int tid  = threadIdx.x;
  const int w    = tid >> 6;
  const int lane = tid & 63;
  const int quad = lane >> 4;
  const int l16  = lane & 15;
  const int qw   = w >> 1;
  const int kw   = w & 1;
  const int key  = l16 & 7;

  // XCD-aware (head, pair) mapping: residue class id&7 hosts head id&7
  // (slots 0..63) plus half of head 8+((id&7)>>1) (slots 64..95).
  const int id = blockIdx.x;
  const int rc = id & 7, slot = id >> 3;
  const int h  = (slot < 64) ? rc : 8 + (rc >> 1);
  const int bx = (slot < 64) ? slot : ((rc & 1) * 32 + (slot - 64));

  const int sr8  = lane >> 3;               // K: row-in-slab
  const int scK  = ((lane & 7) ^ sr8) * 8;  // K: swizzled source col
  const int sr16 = lane >> 4;               // V: row-in-slab

#pragma unroll 1
  for (int side = 0; side < 2; ++side) {
    const int qt = side ? (127 - bx) : bx;
    const int q0 = qt * 32;

    // Q fragments in registers (Qb is L2-hot; no LDS round-trip).
    const u16* qptr = Qb + (size_t)(q0 + qw * 16 + l16) * DIM + h * 64 + quad * 8;
    const bf16x8 aq0 = *(const bf16x8*)(qptr);
    const bf16x8 aq1 = *(const bf16x8*)(qptr + 32);

    f32x4 o[4] = {};
    float l_r[4] = {};

    const int nkt = qt / 2 + 1;          // 64-wide k-tiles
    const int niter = (nkt + 1) >> 1;    // 128-wide slabs
    const int my_last = nkt - 1;         // diagonal tile index

#pragma unroll 1
    for (int i = 0; i < niter; ++i) {
      const int k0g = i * 128;
      __syncthreads();  // all waves done reading Kl/Vl (and Obuf last side)
#pragma unroll
      for (int j = 0; j < 4; ++j)
        gload_lds16(Kb + (size_t)(k0g + w * 32 + j * 8 + sr8) * DIM + h * 64 + scK,
                    &Kl[(w * 32 + j * 8) * 64]);
#pragma unroll
      for (int j = 0; j < 4; ++j) {
        const int vrow = w * 16 + j * 4 + sr16;
        const int vcol = ((lane & 15) ^ (vrow & 7)) * 8;
        gload_lds16(VTb + (size_t)(h * 64 + vrow) * S_LEN + k0g + vcol,
                    &Vl[(w * 16 + j * 4) * 128]);
      }
      __syncthreads();

      const int kt_w = 2 * i + kw;
      if (kt_w < nkt) {
        // S = Q K^T : 16 q-rows x 64 kv (this wave's half)
        f32x4 s[4];
#pragma unroll
        for (int t = 0; t < 4; ++t) {
          const int row = kw * 64 + t * 16 + l16;
          const bf16x8 bk0 = *(const bf16x8*)&Kl[row * 64 + (quad ^ key) * 8];
          const bf16x8 bk1 = *(const bf16x8*)&Kl[row * 64 + ((quad ^ 4) ^ key) * 8];
          s[t] = __builtin_amdgcn_mfma_f32_16x16x32_bf16(
              aq0, bk0, f32x4{0.f, 0.f, 0.f, 0.f}, 0, 0, 0);
          s[t] = __builtin_amdgcn_mfma_f32_16x16x32_bf16(aq1, bk1, s[t], 0, 0, 0);
        }

        // P = 2^S; mask on diagonal tile.
        if (kt_w == my_last) {
#pragma unroll
          for (int t = 0; t < 4; ++t)
#pragma unroll
            for (int r = 0; r < 4; ++r) {
              const int kvg = k0g + kw * 64 + t * 16 + l16;
              const int qg  = q0 + qw * 16 + quad * 4 + r;
              float p = __builtin_amdgcn_exp2f(s[t][r]);
              if (kvg > qg) p = 0.f;
              l_r[r] += p;
              Pl[w][(quad * 4 + r) * 72 + t * 16 + l16] =
                  (u16)((__float_as_uint(p) + 0x8000u) >> 16);
            }
        } else {
#pragma unroll
          for (int t = 0; t < 4; ++t)
#pragma unroll
            for (int r = 0; r < 4; ++r) {
              const float p = __builtin_amdgcn_exp2f(s[t][r]);
              l_r[r] += p;
              Pl[w][(quad * 4 + r) * 72 + t * 16 + l16] =
                  (u16)((__float_as_uint(p) + 0x8000u) >> 16);
            }
        }

        // O += P V (in-wave Pl write->read ordered by lgkmcnt)
        const bf16x8 pa0 = *(const bf16x8*)&Pl[w][l16 * 72 + quad * 8];
        const bf16x8 pa1 = *(const bf16x8*)&Pl[w][l16 * 72 + 32 + quad * 8];
#pragma unroll
        for (int t = 0; t < 4; ++t) {
          const int row = t * 16 + l16;  // d-row in Vl
          const int c0 = (kw * 8 + quad) ^ key;
          const int c1 = (kw * 8 + quad + 4) ^ key;
          const bf16x8 vb0 = *(const bf16x8*)&Vl[row * 128 + c0 * 8];
          const bf16x8 vb1 = *(const bf16x8*)&Vl[row * 128 + c1 * 8];
          o[t] = __builtin_amdgcn_mfma_f32_16x16x32_bf16(pa0, vb0, o[t], 0, 0, 0);
          o[t] = __builtin_amdgcn_mfma_f32_16x16x32_bf16(pa1, vb1, o[t], 0, 0, 0);
        }
      }
    }

    // Combine kv-halves: waves w and w^1 hold partials for the same q-rows.
    // Obuf lane stride 20 floats (16B-aligned, bank starts spread over 8
    // 4-bank groups -> conflict-free; stride 16 hit only banks {0,16}).
    __syncthreads();  // all waves done with Kl/Vl reads before Obuf reuse
    float* Obuf = (float*)KVl;  // 256 lanes x 20 floats = 20 KB (fits 32 KB)
#pragma unroll
    for (int t = 0; t < 4; ++t)
      *(f32x4*)&Obuf[(w * 64 + lane) * 20 + t * 4] = o[t];
    lbuf[w][lane] = float4{l_r[0], l_r[1], l_r[2], l_r[3]};
    __syncthreads();
#pragma unroll
    for (int t = 0; t < 4; ++t) {
      const f32x4 po = *(const f32x4*)&Obuf[((w ^ 1) * 64 + lane) * 20 + t * 4];
      o[t] += po;
    }
    {
      const float4 pl = lbuf[w ^ 1][lane];
      l_r[0] += pl.x; l_r[1] += pl.y; l_r[2] += pl.z; l_r[3] += pl.w;
    }

    if (kw == 0) {
#pragma unroll
      for (int r = 0; r < 4; ++r) {
        float l = l_r[r];
        l += __shfl_xor(l, 1);
        l += __shfl_xor(l, 2);
        l += __shfl_xor(l, 4);
        l += __shfl_xor(l, 8);
        const float inv = 1.f / l;
        const int row = q0 + qw * 16 + quad * 4 + r;
#pragma unroll
        for (int t = 0; t < 4; ++t)
          ctx[(size_t)row * DIM + h * 64 + t * 16 + l16] = f2bf(o[t][r] * inv);
      }
    }
  }
}

// ---------------------------------------------------------------------------
extern "C" void kernel_launch(void* const* d_in, const int* in_sizes, int n_in,
                              void* d_out, int out_size, void* d_ws,
                              size_t ws_size, hipStream_t stream) {
  const float* x  = (const float*)d_in[0];
  const float* wq = (const float*)d_in[1];
  const float* wk = (const float*)d_in[2];
  const float* wv = (const float*)d_in[3];
  const float* wo = (const float*)d_in[4];
  const float* bo = (const float*)d_in[5];

  const size_t n_x = (size_t)S_LEN * DIM;
  const size_t n_w = (size_t)DIM * DIM;
  u16* xb  = (u16*)d_ws;
  u16* wtq = xb + n_x;
  u16* wtk = wtq + n_w;
  u16* wtv = wtk + n_w;
  u16* wto = wtv + n_w;
  u16* Qb  = wto + n_w;
  u16* Kb  = Qb + n_x;
  u16* VTb = Kb + n_x;   // [768][4096]
  u16* ctx = VTb + n_x;

  prep_kernel<<<dim3(12, 12, 5), 256, 0, stream>>>(
      x, wq, wk, wv, wo, xb, wtq, wtk, wtv, wto);

  // Fused QKV: N = 3*768, 128x96 tiles -> 24x32 = 768 blocks (3/CU exact).
  mfma_gemm_kernel<0><<<dim3(24, 32), 256, 0, stream>>>(
      xb, wtq, wtk, wtv, nullptr, Qb, Kb, VTb, nullptr);

  attn_mfma_kernel<<<dim3(768), 256, 0, stream>>>(Qb, Kb, VTb, ctx);

  // Output GEMM: 64x96 tiles -> 8x64 = 512 blocks (2/CU exact), fp32 + bias.
  mfma_gemm_kernel<1><<<dim3(8, 64), 256, 0, stream>>>(
      ctx, wto, nullptr, nullptr, bo, nullptr, nullptr, nullptr, (float*)d_out);
}